// Round 6
// baseline (1099.901 us; speedup 1.0000x reference)
//
#include <hip/hip_runtime.h>
#include <cstddef>

#define LD 33
#define IDX(r,c) ((r)*LD+(c))
#define EPS_TRI 0.01f
#define EPS_BS 1e-4f
#define F4C(v,e) ((e)==0?(v).x:(e)==1?(v).y:(e)==2?(v).z:(v).w)
#define WAVE_FENCE() __builtin_amdgcn_wave_barrier()

// R13: target the <=128-VGPR residency bucket (waves/SIMD halve at 64/128/256;
// R12's 168 sat in the same 2-waves/SIMD bucket as R10's 196 -> no gain).
//  * role 0: pivot-row consumed in float4 chunks (scalar pj read for the pivot
//    element) -> pr_[32] materialization gone (-24 VGPR peak).
//  * role 1: fold split. mrow-fold (needs y) moved BEFORE x-backsub (needs lc)
//    -> y dead before lc[32] loads (-30 VGPR peak). Bit-identical math.
//  * NCH 32 (CSZ 8): 4096 blocks = 16/CU = exactly the 4-waves/SIMD cap
//    (LDS 10240B x 16 = 160KiB exactly). Chains 14 steps.
//  * launch bounds plain (64) — NEVER force min-waves (R10/R11 spill lesson).
#define NCH 32
#define CSZ 8
#define WARM 6

// Swizzled element map for stride-36 LDS matrices (sB, sLl, sLT):
// (row R, col C) lives at float index 36*R + 4*((C>>2) ^ (R&7)) + (C&3).
// Fixes the 4-way bank conflict of float4 accesses at per-lane-varying R.

__device__ __forceinline__ float4 xor1(const float4 v) {
  float4 r;
  r.x = __shfl_xor(v.x, 1);
  r.y = __shfl_xor(v.y, 1);
  r.z = __shfl_xor(v.z, 1);
  r.w = __shfl_xor(v.w, 1);
  return r;
}

// ---------------- Phase 1: Ris[t] = Ri[t] Ri[t]^T, Rm[t] = Ris[t] ms[t] ----------------
__global__ __launch_bounds__(256) void ris_kernel(const float* __restrict__ Ri,
                                                  const float* __restrict__ ms,
                                                  float* __restrict__ Ris,
                                                  float* __restrict__ Rm) {
  const int t = blockIdx.x;
  const int tid = threadIdx.x;
  __shared__ float sR[32*LD];
  __shared__ float sRis[32*LD];
  __shared__ float sm[32];
  {
    const int e = tid * 4;
    const int r = e >> 5, c = e & 31;
    const float4 v = *(const float4*)(Ri + (size_t)t*1024 + e);
    sR[IDX(r,c)+0] = v.x; sR[IDX(r,c)+1] = v.y; sR[IDX(r,c)+2] = v.z; sR[IDX(r,c)+3] = v.w;
    if (tid < 32) sm[tid] = ms[t*32 + tid];
  }
  __syncthreads();
  const int r = tid >> 3, c0 = (tid & 7) * 4;
  float a0=0.f,a1=0.f,a2=0.f,a3=0.f;
#pragma unroll
  for (int p = 0; p < 32; p++) {
    const float rr = sR[IDX(r,p)];
    a0 += rr * sR[IDX(c0+0,p)];
    a1 += rr * sR[IDX(c0+1,p)];
    a2 += rr * sR[IDX(c0+2,p)];
    a3 += rr * sR[IDX(c0+3,p)];
  }
  sRis[IDX(r,c0+0)] = a0; sRis[IDX(r,c0+1)] = a1;
  sRis[IDX(r,c0+2)] = a2; sRis[IDX(r,c0+3)] = a3;
  float4 o; o.x=a0; o.y=a1; o.z=a2; o.w=a3;
  *(float4*)(Ris + (size_t)t*1024 + r*32 + c0) = o;
  __syncthreads();
  if (tid < 32) {
    float acc = 0.f;
#pragma unroll
    for (int j = 0; j < 32; j++) acc += sRis[IDX(tid,j)] * sm[j];
    Rm[t*32 + tid] = acc;
  }
}

// ---------------- Phase 2: parallel precompute of Jdbase, P, h per (n,t) ----------------
__global__ __launch_bounds__(256) void pre_kernel(
    const float* __restrict__ z, const float* __restrict__ A_base,
    const float* __restrict__ b_base, const float* __restrict__ Q_sqrt,
    const float* __restrict__ Ris, const float* __restrict__ Rm,
    float* __restrict__ Jdb, float* __restrict__ Pm, float* __restrict__ h_ws) {
  const int n = blockIdx.x >> 8;
  const int t = blockIdx.x & 255;
  const int tid = threadIdx.x;
  const int r = tid >> 3, c0 = (tid & 7) * 4;
  const bool hcv = (t < 255);
  const bool hpv = (t >= 1);
  __shared__ __align__(16) float sAs[32*LD], sQs[32*LD], sQsp[32*LD];
  __shared__ __align__(16) float sQis[32*LD], sQisp[32*LD], sP[32*LD];
  __shared__ float s_z[16];
  __shared__ float s_bs[32], s_bsp[32];
  if (tid < 8)       s_z[tid] = hcv ? z[((size_t)n << 11) + t*8 + tid] : 0.f;
  else if (tid < 16) s_z[tid] = hpv ? z[((size_t)n << 11) + (t-1)*8 + (tid-8)] : 0.f;
  __syncthreads();
  {
    float a0=0,a1=0,a2=0,a3=0,q0=0,q1=0,q2=0,q3=0,p0=0,p1=0,p2=0,p3=0;
#pragma unroll
    for (int kq = 0; kq < 8; kq++) {
      const float zc = s_z[kq], zp = s_z[8+kq];
      const float4 av = *(const float4*)(A_base + kq*1024 + r*32 + c0);
      const float4 qv = *(const float4*)(Q_sqrt + kq*1024 + r*32 + c0);
      a0 += zc*av.x; a1 += zc*av.y; a2 += zc*av.z; a3 += zc*av.w;
      q0 += zc*qv.x; q1 += zc*qv.y; q2 += zc*qv.z; q3 += zc*qv.w;
      p0 += zp*qv.x; p1 += zp*qv.y; p2 += zp*qv.z; p3 += zp*qv.w;
    }
    sAs[IDX(r,c0+0)]=a0; sAs[IDX(r,c0+1)]=a1; sAs[IDX(r,c0+2)]=a2; sAs[IDX(r,c0+3)]=a3;
    sQs[IDX(r,c0+0)]=q0; sQs[IDX(r,c0+1)]=q1; sQs[IDX(r,c0+2)]=q2; sQs[IDX(r,c0+3)]=q3;
    sQsp[IDX(r,c0+0)]=p0; sQsp[IDX(r,c0+1)]=p1; sQsp[IDX(r,c0+2)]=p2; sQsp[IDX(r,c0+3)]=p3;
    if (tid < 32) {
      float b = 0.f;
#pragma unroll
      for (int kq = 0; kq < 8; kq++) b += s_z[kq] * b_base[kq*32 + tid];
      s_bs[tid] = b;
    } else if (tid < 64) {
      const int i = tid - 32;
      float b = 0.f;
#pragma unroll
      for (int kq = 0; kq < 8; kq++) b += s_z[8+kq] * b_base[kq*32 + i];
      s_bsp[i] = b;
    }
  }
  __syncthreads();
  {
    float a0=0,a1=0,a2=0,a3=0,b0=0,b1=0,b2=0,b3=0;
#pragma unroll
    for (int p = 0; p < 32; p++) {
      const float qr = sQs[IDX(r,p)];
      a0 += qr * sQs[IDX(c0+0,p)];
      a1 += qr * sQs[IDX(c0+1,p)];
      a2 += qr * sQs[IDX(c0+2,p)];
      a3 += qr * sQs[IDX(c0+3,p)];
      const float pr2 = sQsp[IDX(r,p)];
      b0 += pr2 * sQsp[IDX(c0+0,p)];
      b1 += pr2 * sQsp[IDX(c0+1,p)];
      b2 += pr2 * sQsp[IDX(c0+2,p)];
      b3 += pr2 * sQsp[IDX(c0+3,p)];
    }
    sQis[IDX(r,c0+0)]=a0; sQis[IDX(r,c0+1)]=a1; sQis[IDX(r,c0+2)]=a2; sQis[IDX(r,c0+3)]=a3;
    sQisp[IDX(r,c0+0)]=b0; sQisp[IDX(r,c0+1)]=b1; sQisp[IDX(r,c0+2)]=b2; sQisp[IDX(r,c0+3)]=b3;
  }
  __syncthreads();
  {
    float a0=0,a1=0,a2=0,a3=0;
#pragma unroll
    for (int p = 0; p < 32; p++) {
      const float qr = sQis[IDX(r,p)];
      a0 += qr * sAs[IDX(p,c0+0)];
      a1 += qr * sAs[IDX(p,c0+1)];
      a2 += qr * sAs[IDX(p,c0+2)];
      a3 += qr * sAs[IDX(p,c0+3)];
    }
    sP[IDX(r,c0+0)]=a0; sP[IDX(r,c0+1)]=a1; sP[IDX(r,c0+2)]=a2; sP[IDX(r,c0+3)]=a3;
    if (hcv) {
      float4 v; v.x=a0; v.y=a1; v.z=a2; v.w=a3;
      *(float4*)(Pm + ((size_t)(n*255 + t))*1024 + r*32 + c0) = v;
    }
  }
  __syncthreads();
  {
    const float4 rv = *(const float4*)(Ris + (size_t)t*1024 + r*32 + c0);
    float j0 = rv.x, j1 = rv.y, j2 = rv.z, j3 = rv.w;
    if (r == c0+0) j0 += EPS_TRI;
    else if (r == c0+1) j1 += EPS_TRI;
    else if (r == c0+2) j2 += EPS_TRI;
    else if (r == c0+3) j3 += EPS_TRI;
    if (hcv) {
#pragma unroll
      for (int p = 0; p < 32; p++) {
        const float ar = sAs[IDX(p,r)];
        j0 += ar * sP[IDX(p,c0+0)];
        j1 += ar * sP[IDX(p,c0+1)];
        j2 += ar * sP[IDX(p,c0+2)];
        j3 += ar * sP[IDX(p,c0+3)];
      }
    }
    if (hpv) {
      j0 += sQisp[IDX(r,c0+0)];
      j1 += sQisp[IDX(r,c0+1)];
      j2 += sQisp[IDX(r,c0+2)];
      j3 += sQisp[IDX(r,c0+3)];
    }
    float4 v; v.x=j0; v.y=j1; v.z=j2; v.w=j3;
    *(float4*)(Jdb + ((size_t)(n*256 + t))*1024 + r*32 + c0) = v;
    if (tid < 32) {
      float h = Rm[t*32 + tid];
      if (hcv) {
        float a = 0.f;
#pragma unroll
        for (int j = 0; j < 32; j++) a += sP[IDX(tid,j)] * s_bs[j];
        h -= a;
      }
      if (hpv) {
        float a = 0.f;
#pragma unroll
        for (int j = 0; j < 32; j++) a += sQisp[IDX(tid,j)] * s_bsp[j];
        h += a;
      }
      h_ws[((size_t)(n*256 + t))*32 + tid] = h;
    }
  }
}

// ---------------- Phase 3: chunked chains ----------------
union __align__(16) ChainShared {
  struct {
    float sCT[32*36];
    float sB[32*36];
    float sPiv[64];
    float s_rhs[32], s_d[32], s_invp[32];
  } r0;
  struct {
    float sLl[32*36];
    float sLT[32*36];
    float sCol[32];
    float s_x[32], s_invd[32], s_invr[32];
  } r1;
};

__global__ __launch_bounds__(64) void chain_kernel(
    const float* __restrict__ Jdb, const float* __restrict__ Pm,
    const float* __restrict__ h_ws, const float* __restrict__ noise,
    float* __restrict__ c_ws, float* __restrict__ d_ws, float* __restrict__ x_ws) {
  const int bid  = blockIdx.x;
  const int role = (bid >= 64*NCH) ? 1 : 0;
  const int rem  = bid - role*64*NCH;
  const int bn   = rem & 63;
  const int ch   = rem >> 6;            // 0..NCH-1
  const int lane = threadIdx.x;
  const int r    = lane >> 1;
  const int h2   = lane & 1;
  const int c16  = h2 * 16;

  const int k_out     = ch * CSZ;
  const int k_start   = (ch == 0) ? 0 : (k_out - WARM);
  const int k_end_raw = k_out + CSZ;
  const int k_end     = (k_end_raw > 256) ? 256 : k_end_raw;

  const float* Jb = Jdb + (size_t)bn * 256 * 1024;
  const float* Pb = Pm  + (size_t)bn * 255 * 1024;

  __shared__ ChainShared su;

  if (role == 0) {
    // ============ GJ chain: J_k = Jdb_k + P_{k-1} c_{k-1}; staged-pivot Gauss-Jordan ============
    float* sCT = su.r0.sCT;
    float* sB  = su.r0.sB;
    float* sPiv = su.r0.sPiv;
    float* s_rhs = su.r0.s_rhs;
    float* s_d   = su.r0.s_d;
    float* s_invp = su.r0.s_invp;
    const float* hb = h_ws + (size_t)bn * 256 * 32;

    const int offO = c16;        // own P half pairs matrix cols c16..c16+15
    const int offX = 16 - c16;   // partner half pairs the other 16 cols

    float jrow[16]; float4 pq[4]; float hq;
    {
      float4 j4[4];
#pragma unroll
      for (int q = 0; q < 4; q++) j4[q] = *(const float4*)(Jb + (size_t)k_start*1024 + r*32 + c16 + 4*q);
#pragma unroll
      for (int q = 0; q < 4; q++) pq[q] = *(const float4*)(Pb + (size_t)k_start*1024 + r*32 + c16 + 4*q);
      hq = hb[k_start*32 + r];
#pragma unroll
      for (int i = 0; i < 16; i++) jrow[i] = F4C(j4[i >> 2], i & 3);
    }

    for (int k = k_start; k < k_end; k++) {
      // prefetch k+1 as raw float4 — untouched until the fold at end of step
      float4 jn4[4], pn[4]; float hn = 0.f;
      if (k + 1 < 256) {
#pragma unroll
        for (int q = 0; q < 4; q++)
          jn4[q] = *(const float4*)(Jb + (size_t)(k+1)*1024 + r*32 + c16 + 4*q);
        hn = hb[(k+1)*32 + r];
        if (k + 1 < 255) {
#pragma unroll
          for (int q = 0; q < 4; q++)
            pn[q] = *(const float4*)(Pb + (size_t)(k+1)*1024 + r*32 + c16 + 4*q);
        }
      }
      // rhs already fully assembled in hq
      if (h2 == 0) s_rhs[r] = hq;
      // register layout: h2=0 lane holds J row r (32), h2=1 lane holds B row r (32)
      float g[32];
      if (h2 == 1) {
#pragma unroll
        for (int i = 0; i < 32; i++) g[i] = (i == r) ? 1.f : 0.f;
      }
#pragma unroll
      for (int i = 0; i < 16; i++) {
        const float oth = __shfl_xor(jrow[i], 1);
        if (h2 == 0) { g[i] = jrow[i]; g[16+i] = oth; }
      }
      // stage row 0 (J half to sPiv[0:32], B half to sPiv[32:64])
      if (r == 0) {
#pragma unroll
        for (int q = 0; q < 8; q++) {
          float4 v; v.x=g[4*q]; v.y=g[4*q+1]; v.z=g[4*q+2]; v.w=g[4*q+3];
          *(float4*)(&sPiv[h2*32 + 4*q]) = v;
        }
      }
      WAVE_FENCE();
      // Gauss-Jordan with LDS-staged pivot row.
      // R13: pivot element via scalar read; update consumes pivot row in
      // float4 chunks -> no pr_[32] materialization (VGPR peak cut).
      float my_piv = 1.f;
#pragma unroll
      for (int j = 0; j < 32; j++) {
        const float pj_own = sPiv[h2*32 + j];           // J[j][j] on h2=0
        const float pj_oth = __shfl_xor(pj_own, 1);
        const float dpiv = h2 ? pj_oth : pj_own;
        const float ip = __builtin_amdgcn_rcpf(dpiv);
        const float gj_own = g[j];                      // J[r][j] on h2=0
        const float gj_oth = __shfl_xor(gj_own, 1);
        float f = (h2 ? gj_oth : gj_own) * ip;
        if (j == r) { my_piv = dpiv; f = 0.f; }
#pragma unroll
        for (int q = 0; q < 8; q++) {
          const float4 v = *(const float4*)(&sPiv[h2*32 + 4*q]);
          g[4*q+0] -= f * v.x;
          g[4*q+1] -= f * v.y;
          g[4*q+2] -= f * v.z;
          g[4*q+3] -= f * v.w;
        }
        if (j + 1 < 32) {
          WAVE_FENCE();
          if (r == j + 1) {
#pragma unroll
            for (int q = 0; q < 8; q++) {
              float4 v; v.x=g[4*q]; v.y=g[4*q+1]; v.z=g[4*q+2]; v.w=g[4*q+3];
              *(float4*)(&sPiv[h2*32 + 4*q]) = v;
            }
          }
          WAVE_FENCE();
        }
      }
      const float ipv = __builtin_amdgcn_rcpf(my_piv);
      if (h2 == 0) s_invp[r] = ipv;
      else {
        const int s7 = r & 7;
#pragma unroll
        for (int q = 0; q < 8; q++) {
          float4 v; v.x=g[4*q]; v.y=g[4*q+1]; v.z=g[4*q+2]; v.w=g[4*q+3];
          *(float4*)(&sB[r*36 + 4*(q ^ s7)]) = v;      // swizzled B row write
        }
      }
      WAVE_FENCE();
      // d_k = invp .* (B rhs)
      if (h2 == 1) {
        float acc = 0.f;
#pragma unroll
        for (int q = 0; q < 8; q++) {
          const float4 rv = *(const float4*)(&s_rhs[4*q]);
          acc += g[4*q]*rv.x + g[4*q+1]*rv.y + g[4*q+2]*rv.z + g[4*q+3]*rv.w;
        }
        const float dv = acc * ipv;
        s_d[r] = dv;
        if (k >= k_out) d_ws[((size_t)(bn*256 + k))*32 + r] = dv;
      }
      // c_k = -(P_k B^T) col-scaled by invp  (address-select)
      float4 poK[4];
      if (k < 255) {
#pragma unroll
        for (int q = 0; q < 4; q++) poK[q] = xor1(pq[q]);
        float outv[16];
#pragma unroll
        for (int i = 0; i < 16; i++) {
          const int c = c16 + i;
          const float* bb = &sB[c*36];
          const int s7 = c & 7;
          float acc = 0.f;
#pragma unroll
          for (int q = 0; q < 4; q++) {
            const float4 v0 = *(const float4*)(bb + 4*((4*h2 + q) ^ s7));       // B[c][c16+4q..]
            acc += pq[q].x*v0.x + pq[q].y*v0.y + pq[q].z*v0.z + pq[q].w*v0.w;
            const float4 v1 = *(const float4*)(bb + 4*(((4 - 4*h2) + q) ^ s7)); // B[c][(16-c16)+4q..]
            acc += poK[q].x*v1.x + poK[q].y*v1.y + poK[q].z*v1.z + poK[q].w*v1.w;
          }
          outv[i] = -acc * s_invp[c];
        }
        if (k >= k_out) {
#pragma unroll
          for (int q = 0; q < 4; q++) {
            float4 v; v.x=outv[4*q]; v.y=outv[4*q+1]; v.z=outv[4*q+2]; v.w=outv[4*q+3];
            *(float4*)(c_ws + ((size_t)(bn*255 + k))*1024 + r*32 + c16 + 4*q) = v;
          }
        }
#pragma unroll
        for (int i = 0; i < 16; i++) sCT[(c16+i)*36 + r] = outv[i];
      }
      WAVE_FENCE();
      // fold for k+1: jrow = Jdb_{k+1} + P_k c_k ; hq = h_{k+1} + P_k d_k
      if (k + 1 < k_end) {
        float a_own = 0.f;
#pragma unroll
        for (int q = 0; q < 4; q++) {
          const float4 dv = *(const float4*)(&s_d[c16 + 4*q]);
          a_own += pq[q].x*dv.x + pq[q].y*dv.y + pq[q].z*dv.z + pq[q].w*dv.w;
        }
        hq = hn + a_own + __shfl_xor(a_own, 1);
#pragma unroll
        for (int i = 0; i < 16; i++) {
          const float* base = &sCT[(c16 + i) * 36];
          float acc = F4C(jn4[i >> 2], i & 3);
#pragma unroll
          for (int q = 0; q < 4; q++) {
            const float4 v0 = *(const float4*)(base + offO + 4*q);
            acc += pq[q].x*v0.x + pq[q].y*v0.y + pq[q].z*v0.z + pq[q].w*v0.w;
            const float4 v1 = *(const float4*)(base + offX + 4*q);
            acc += poK[q].x*v1.x + poK[q].y*v1.y + poK[q].z*v1.z + poK[q].w*v1.w;
          }
          jrow[i] = acc;
        }
#pragma unroll
        for (int q = 0; q < 4; q++) pq[q] = pn[q];
      }
    }
  } else {
    // ============ chol chain: M_k = Jdb_k - Ll Ll^T; staged-column Cholesky; L, Ll, x ============
    float* sLl = su.r1.sLl;
    float* sLT = su.r1.sLT;
    float* sCol = su.r1.sCol;
    float* s_x = su.r1.s_x;
    float* s_invd = su.r1.s_invd;
    float* s_invr = su.r1.s_invr;
    const float* nb = noise + (size_t)bn * 8192;

    float mrow[16]; float4 pq[4]; float xr;
    {
      float4 j4[4];
#pragma unroll
      for (int q = 0; q < 4; q++) j4[q] = *(const float4*)(Jb + (size_t)k_start*1024 + r*32 + c16 + 4*q);
#pragma unroll
      for (int q = 0; q < 4; q++) pq[q] = *(const float4*)(Pb + (size_t)k_start*1024 + r*32 + c16 + 4*q);
      xr = nb[k_start*32 + r];
#pragma unroll
      for (int i = 0; i < 16; i++) mrow[i] = F4C(j4[i >> 2], i & 3);
    }

    for (int k = k_start; k < k_end; k++) {
      float4 jn4[4], pn[4]; float nn = 0.f;
      if (k + 1 < 256) {
#pragma unroll
        for (int q = 0; q < 4; q++)
          jn4[q] = *(const float4*)(Jb + (size_t)(k+1)*1024 + r*32 + c16 + 4*q);
        nn = nb[(k+1)*32 + r];
        if (k + 1 < 255) {
#pragma unroll
          for (int q = 0; q < 4; q++)
            pn[q] = *(const float4*)(Pb + (size_t)(k+1)*1024 + r*32 + c16 + 4*q);
        }
      }
      // cholesky on mrow with LDS-staged pivot column
#pragma unroll
      for (int j = 0; j < 32; j++) {
        const int jl = j & 15, jh = j >> 4;
        WAVE_FENCE();
        if (h2 == jh) sCol[r] = mrow[jl];       // stage column j (pre-update snapshot)
        WAVE_FENCE();
        const float dpiv = sCol[j];
        const float fr   = sCol[r];
        const float sq = sqrtf(dpiv);
        const float inv = __builtin_amdgcn_rcpf(sq);
        if (h2 == 0 && r >= j) sLT[36*j + 4*((r>>2) ^ (j&7)) + (r&3)] = (r == j) ? sq : fr*inv;
        if (lane == 0) { s_invd[j] = inv; s_invr[j] = __builtin_amdgcn_rcpf(sq + EPS_BS); }
        const float s2 = (r > j) ? fr*inv*inv : 0.f;
#pragma unroll
        for (int q = 0; q < 4; q++) {
          const float4 cc = *(const float4*)(&sCol[c16 + 4*q]);
          mrow[4*q+0] -= s2 * cc.x;
          mrow[4*q+1] -= s2 * cc.y;
          mrow[4*q+2] -= s2 * cc.z;
          mrow[4*q+3] -= s2 * cc.w;
        }
      }
      WAVE_FENCE();
      // Ll row r: solve L^T y = -P[r,:]^T  (backward); y kept in regs for the
      // mrow-fold that immediately follows (R13: fold split so y dies before lc loads)
      float y[32];
      if (k < 255) {
#pragma unroll
        for (int j = 31; j >= 0; j--) {
          const float own = F4C(pq[(j & 15) >> 2], j & 3);
          const float oth = __shfl_xor(own, 1);
          const float pv = ((j >> 4) == h2) ? own : oth;
          float ssum = 0.f;
          const int sj = j & 7;
#pragma unroll
          for (int qq = (j + 1) >> 2; qq < 8; qq++) {
            const float4 v = *(const float4*)(&sLT[36*j + 4*(qq ^ sj)]);
#pragma unroll
            for (int e2 = 0; e2 < 4; e2++) {
              const int p = 4*qq + e2;
              if (p > j) ssum += F4C(v, e2) * y[p];
            }
          }
          y[j] = (-pv - ssum) * s_invd[j];
        }
        if (h2 == 0) {
          const int s7r = r & 7;
#pragma unroll
          for (int q = 0; q < 8; q++) {
            float4 v; v.x=y[4*q]; v.y=y[4*q+1]; v.z=y[4*q+2]; v.w=y[4*q+3];
            *(float4*)(&sLl[36*r + 4*(q ^ s7r)]) = v;
          }
        }
      }
      WAVE_FENCE();
      // mrow-fold (moved BEFORE x-backsub): mrow = Jdb_{k+1} - Ll_k Ll_k^T
      // (needs y + sLl; does NOT need x) -> y dead before lc[32] is loaded.
      if (k + 1 < k_end) {
#pragma unroll
        for (int i = 0; i < 16; i++) {
          const int c = c16 + i;
          const int s7c = c & 7;
          float acc = 0.f;
#pragma unroll
          for (int q = 0; q < 8; q++) {
            const float4 v = *(const float4*)(&sLl[36*c + 4*(q ^ s7c)]);
            acc += y[4*q]*v.x + y[4*q+1]*v.y + y[4*q+2]*v.z + y[4*q+3]*v.w;
          }
          mrow[i] = F4C(jn4[i >> 2], i & 3) - acc;
        }
      }
      // x back-substitution: (L+eps)^T x = xr
      {
        float lc[32];
        const int s7r = r & 7;
#pragma unroll
        for (int q = 0; q < 8; q++) {
          const float4 v = *(const float4*)(&sLT[36*r + 4*(q ^ s7r)]);
          lc[4*q]=v.x; lc[4*q+1]=v.y; lc[4*q+2]=v.z; lc[4*q+3]=v.w;
        }
        float xp = xr;
        float myx = 0.f;
#pragma unroll
        for (int j = 31; j >= 0; j--) {
          const float xj = __shfl(xp * s_invr[j], 2*j);
          if (j == r) myx = xj;
          if (r < j) xp -= lc[j] * xj;
        }
        if (h2 == 0) {
          s_x[r] = myx;
          if (k >= k_out) x_ws[((size_t)(bn*256 + k))*32 + r] = myx;
        }
      }
      WAVE_FENCE();
      // xr-fold: xr = z_{k+1} - Ll_k^T x_k  (reads y back from sLl — bit-identical)
      if (k + 1 < k_end) {
        float a_own = 0.f;
        const int rg = r >> 2, re = r & 3;
#pragma unroll
        for (int jj = 0; jj < 16; jj++)
          a_own += sLl[36*(c16+jj) + 4*(rg ^ (jj & 7)) + re] * s_x[c16+jj];
        xr = nn - (a_own + __shfl_xor(a_own, 1));
#pragma unroll
        for (int q = 0; q < 4; q++) pq[q] = pn[q];
      }
    }
  }
}

// ---------------- Phase 4: chunked backward mu scan + output = x + mu (single-wave) ----------
// Seed depth 8: mu contraction <= 0.15/step => seed residual ~2.6e-7, invisible.
__global__ __launch_bounds__(64) void bwd_kernel(const float* __restrict__ c_ws,
                                                 const float* __restrict__ d_ws,
                                                 const float* __restrict__ x_ws,
                                                 float* __restrict__ out) {
  const int bn = blockIdx.x >> 4;
  const int q  = blockIdx.x & 15;
  const int lane = threadIdx.x;
  const int r = lane >> 1, h2 = lane & 1, c16 = h2 * 16;
  const int k_lo = q * 16;
  const int k_seed = (q == 15) ? 255 : (k_lo + 23);
  __shared__ float s_mu[32];
  if (h2 == 0) {
    const float mu = d_ws[((size_t)(bn*256 + k_seed))*32 + r];
    s_mu[r] = mu;
    if (k_seed == 255)
      out[((size_t)(bn*256 + 255))*32 + r] = x_ws[((size_t)(bn*256 + 255))*32 + r] + mu;
  }
  WAVE_FENCE();
  for (int k = k_seed - 1; k >= k_lo; k--) {
    const float* cp = c_ws + ((size_t)(bn*255 + k))*1024 + r*32 + c16;
    const float4 v0 = *(const float4*)(cp + 0);
    const float4 v1 = *(const float4*)(cp + 4);
    const float4 v2 = *(const float4*)(cp + 8);
    const float4 v3 = *(const float4*)(cp + 12);
    float part = v0.x*s_mu[c16+0] + v0.y*s_mu[c16+1] + v0.z*s_mu[c16+2] + v0.w*s_mu[c16+3]
               + v1.x*s_mu[c16+4] + v1.y*s_mu[c16+5] + v1.z*s_mu[c16+6] + v1.w*s_mu[c16+7]
               + v2.x*s_mu[c16+8] + v2.y*s_mu[c16+9] + v2.z*s_mu[c16+10]+ v2.w*s_mu[c16+11]
               + v3.x*s_mu[c16+12]+ v3.y*s_mu[c16+13]+ v3.z*s_mu[c16+14]+ v3.w*s_mu[c16+15];
    part += __shfl_xor(part, 1);
    float mu = 0.f, xv = 0.f;
    if (h2 == 0) {
      mu = d_ws[((size_t)(bn*256 + k))*32 + r] - part;
      xv = x_ws[((size_t)(bn*256 + k))*32 + r];
    }
    WAVE_FENCE();
    if (h2 == 0) {
      s_mu[r] = mu;
      if (k < k_lo + 16) out[((size_t)(bn*256 + k))*32 + r] = xv + mu;
    }
    WAVE_FENCE();
  }
}

extern "C" void kernel_launch(void* const* d_in, const int* in_sizes, int n_in,
                              void* d_out, int out_size, void* d_ws, size_t ws_size,
                              hipStream_t stream) {
  const float* z      = (const float*)d_in[0];   // (64,256,8)
  const float* A_base = (const float*)d_in[1];   // (8,32,32)
  const float* b_base = (const float*)d_in[2];   // (8,32)
  const float* Q_sqrt = (const float*)d_in[3];   // (8,32,32)
  const float* ms     = (const float*)d_in[4];   // (256,32)
  const float* Ri     = (const float*)d_in[5];   // (256,32,32)
  const float* noise  = (const float*)d_in[6];   // (64,8192)
  float* out = (float*)d_out;

  float* ws = (float*)d_ws;
  const size_t SZ_C = (size_t)64*255*1024;
  const size_t SZ_J = (size_t)64*256*1024;
  const size_t SZ_V = (size_t)64*256*32;

  float* c_ws  = ws;
  float* Jdb   = c_ws + SZ_C;
  float* Pm    = Jdb + SZ_J;
  float* hbuf  = Pm + SZ_C;
  float* d_vec = hbuf + SZ_V;
  float* x_vec = d_vec + SZ_V;
  float* Ris   = x_vec + SZ_V;
  float* Rm    = Ris + (size_t)256*1024;

  ris_kernel<<<256, 256, 0, stream>>>(Ri, ms, Ris, Rm);
  pre_kernel<<<16384, 256, 0, stream>>>(z, A_base, b_base, Q_sqrt, Ris, Rm, Jdb, Pm, hbuf);
  chain_kernel<<<2*64*NCH, 64, 0, stream>>>(Jdb, Pm, hbuf, noise, c_ws, d_vec, x_vec);
  bwd_kernel<<<1024, 64, 0, stream>>>(c_ws, d_vec, x_vec, out);
}

// Round 7
// 1028.968 us; speedup vs baseline: 1.0689x; 1.0689x over previous
//
#include <hip/hip_runtime.h>
#include <cstddef>

#define LD 33
#define IDX(r,c) ((r)*LD+(c))
#define EPS_TRI 0.01f
#define EPS_BS 1e-4f
#define F4C(v,e) ((e)==0?(v).x:(e)==1?(v).y:(e)==2?(v).z:(v).w)
#define WAVE_FENCE() __builtin_amdgcn_wave_barrier()

// R14: abandon the VGPR-bucket chase (R11 forced->spill; R12/R13 voluntary->no
// bucket change). Evidence instead: R10's NCH16 geometry (2048 blocks = exact
// residency at 2 waves/SIMD) is fastest; Occupancy ~12% << 25% => role-1 tail.
//  * Role 1 Ll-solve rewritten as column-sweep back-substitution: lanes own
//    columns of X=Ll^T (= rows of Ll). Per pivot: 1 mul + 1 DPP shfl + <=4
//    broadcast b128 reads of L-row-j (new sLrow, filled during chol) + masked
//    FMAs. Replaces 32 serial LDS round trips (~6.4K cyc) with ~1.5K pipelined.
//  * Per-role chunking: role0 = 14 chunks x 19 (25-step chains), role1 = 18
//    chunks x 15 (21-step chains) -> 2048 blocks total, balanced retirement.
//  * Role 0 byte-identical to R13 (measured correct).
#define NCH0 14
#define CSZ0 19
#define NCH1 18
#define CSZ1 15
#define WARM 6

// Swizzled element map for stride-36 LDS matrices (sB, sLl, sLT, sLrow):
// (row R, col C) lives at float index 36*R + 4*((C>>2) ^ (R&7)) + (C&3).

__device__ __forceinline__ float4 xor1(const float4 v) {
  float4 r;
  r.x = __shfl_xor(v.x, 1);
  r.y = __shfl_xor(v.y, 1);
  r.z = __shfl_xor(v.z, 1);
  r.w = __shfl_xor(v.w, 1);
  return r;
}

// ---------------- Phase 1: Ris[t] = Ri[t] Ri[t]^T, Rm[t] = Ris[t] ms[t] ----------------
__global__ __launch_bounds__(256) void ris_kernel(const float* __restrict__ Ri,
                                                  const float* __restrict__ ms,
                                                  float* __restrict__ Ris,
                                                  float* __restrict__ Rm) {
  const int t = blockIdx.x;
  const int tid = threadIdx.x;
  __shared__ float sR[32*LD];
  __shared__ float sRis[32*LD];
  __shared__ float sm[32];
  {
    const int e = tid * 4;
    const int r = e >> 5, c = e & 31;
    const float4 v = *(const float4*)(Ri + (size_t)t*1024 + e);
    sR[IDX(r,c)+0] = v.x; sR[IDX(r,c)+1] = v.y; sR[IDX(r,c)+2] = v.z; sR[IDX(r,c)+3] = v.w;
    if (tid < 32) sm[tid] = ms[t*32 + tid];
  }
  __syncthreads();
  const int r = tid >> 3, c0 = (tid & 7) * 4;
  float a0=0.f,a1=0.f,a2=0.f,a3=0.f;
#pragma unroll
  for (int p = 0; p < 32; p++) {
    const float rr = sR[IDX(r,p)];
    a0 += rr * sR[IDX(c0+0,p)];
    a1 += rr * sR[IDX(c0+1,p)];
    a2 += rr * sR[IDX(c0+2,p)];
    a3 += rr * sR[IDX(c0+3,p)];
  }
  sRis[IDX(r,c0+0)] = a0; sRis[IDX(r,c0+1)] = a1;
  sRis[IDX(r,c0+2)] = a2; sRis[IDX(r,c0+3)] = a3;
  float4 o; o.x=a0; o.y=a1; o.z=a2; o.w=a3;
  *(float4*)(Ris + (size_t)t*1024 + r*32 + c0) = o;
  __syncthreads();
  if (tid < 32) {
    float acc = 0.f;
#pragma unroll
    for (int j = 0; j < 32; j++) acc += sRis[IDX(tid,j)] * sm[j];
    Rm[t*32 + tid] = acc;
  }
}

// ---------------- Phase 2: parallel precompute of Jdbase, P, h per (n,t) ----------------
__global__ __launch_bounds__(256) void pre_kernel(
    const float* __restrict__ z, const float* __restrict__ A_base,
    const float* __restrict__ b_base, const float* __restrict__ Q_sqrt,
    const float* __restrict__ Ris, const float* __restrict__ Rm,
    float* __restrict__ Jdb, float* __restrict__ Pm, float* __restrict__ h_ws) {
  const int n = blockIdx.x >> 8;
  const int t = blockIdx.x & 255;
  const int tid = threadIdx.x;
  const int r = tid >> 3, c0 = (tid & 7) * 4;
  const bool hcv = (t < 255);
  const bool hpv = (t >= 1);
  __shared__ __align__(16) float sAs[32*LD], sQs[32*LD], sQsp[32*LD];
  __shared__ __align__(16) float sQis[32*LD], sQisp[32*LD], sP[32*LD];
  __shared__ float s_z[16];
  __shared__ float s_bs[32], s_bsp[32];
  if (tid < 8)       s_z[tid] = hcv ? z[((size_t)n << 11) + t*8 + tid] : 0.f;
  else if (tid < 16) s_z[tid] = hpv ? z[((size_t)n << 11) + (t-1)*8 + (tid-8)] : 0.f;
  __syncthreads();
  {
    float a0=0,a1=0,a2=0,a3=0,q0=0,q1=0,q2=0,q3=0,p0=0,p1=0,p2=0,p3=0;
#pragma unroll
    for (int kq = 0; kq < 8; kq++) {
      const float zc = s_z[kq], zp = s_z[8+kq];
      const float4 av = *(const float4*)(A_base + kq*1024 + r*32 + c0);
      const float4 qv = *(const float4*)(Q_sqrt + kq*1024 + r*32 + c0);
      a0 += zc*av.x; a1 += zc*av.y; a2 += zc*av.z; a3 += zc*av.w;
      q0 += zc*qv.x; q1 += zc*qv.y; q2 += zc*qv.z; q3 += zc*qv.w;
      p0 += zp*qv.x; p1 += zp*qv.y; p2 += zp*qv.z; p3 += zp*qv.w;
    }
    sAs[IDX(r,c0+0)]=a0; sAs[IDX(r,c0+1)]=a1; sAs[IDX(r,c0+2)]=a2; sAs[IDX(r,c0+3)]=a3;
    sQs[IDX(r,c0+0)]=q0; sQs[IDX(r,c0+1)]=q1; sQs[IDX(r,c0+2)]=q2; sQs[IDX(r,c0+3)]=q3;
    sQsp[IDX(r,c0+0)]=p0; sQsp[IDX(r,c0+1)]=p1; sQsp[IDX(r,c0+2)]=p2; sQsp[IDX(r,c0+3)]=p3;
    if (tid < 32) {
      float b = 0.f;
#pragma unroll
      for (int kq = 0; kq < 8; kq++) b += s_z[kq] * b_base[kq*32 + tid];
      s_bs[tid] = b;
    } else if (tid < 64) {
      const int i = tid - 32;
      float b = 0.f;
#pragma unroll
      for (int kq = 0; kq < 8; kq++) b += s_z[8+kq] * b_base[kq*32 + i];
      s_bsp[i] = b;
    }
  }
  __syncthreads();
  {
    float a0=0,a1=0,a2=0,a3=0,b0=0,b1=0,b2=0,b3=0;
#pragma unroll
    for (int p = 0; p < 32; p++) {
      const float qr = sQs[IDX(r,p)];
      a0 += qr * sQs[IDX(c0+0,p)];
      a1 += qr * sQs[IDX(c0+1,p)];
      a2 += qr * sQs[IDX(c0+2,p)];
      a3 += qr * sQs[IDX(c0+3,p)];
      const float pr2 = sQsp[IDX(r,p)];
      b0 += pr2 * sQsp[IDX(c0+0,p)];
      b1 += pr2 * sQsp[IDX(c0+1,p)];
      b2 += pr2 * sQsp[IDX(c0+2,p)];
      b3 += pr2 * sQsp[IDX(c0+3,p)];
    }
    sQis[IDX(r,c0+0)]=a0; sQis[IDX(r,c0+1)]=a1; sQis[IDX(r,c0+2)]=a2; sQis[IDX(r,c0+3)]=a3;
    sQisp[IDX(r,c0+0)]=b0; sQisp[IDX(r,c0+1)]=b1; sQisp[IDX(r,c0+2)]=b2; sQisp[IDX(r,c0+3)]=b3;
  }
  __syncthreads();
  {
    float a0=0,a1=0,a2=0,a3=0;
#pragma unroll
    for (int p = 0; p < 32; p++) {
      const float qr = sQis[IDX(r,p)];
      a0 += qr * sAs[IDX(p,c0+0)];
      a1 += qr * sAs[IDX(p,c0+1)];
      a2 += qr * sAs[IDX(p,c0+2)];
      a3 += qr * sAs[IDX(p,c0+3)];
    }
    sP[IDX(r,c0+0)]=a0; sP[IDX(r,c0+1)]=a1; sP[IDX(r,c0+2)]=a2; sP[IDX(r,c0+3)]=a3;
    if (hcv) {
      float4 v; v.x=a0; v.y=a1; v.z=a2; v.w=a3;
      *(float4*)(Pm + ((size_t)(n*255 + t))*1024 + r*32 + c0) = v;
    }
  }
  __syncthreads();
  {
    const float4 rv = *(const float4*)(Ris + (size_t)t*1024 + r*32 + c0);
    float j0 = rv.x, j1 = rv.y, j2 = rv.z, j3 = rv.w;
    if (r == c0+0) j0 += EPS_TRI;
    else if (r == c0+1) j1 += EPS_TRI;
    else if (r == c0+2) j2 += EPS_TRI;
    else if (r == c0+3) j3 += EPS_TRI;
    if (hcv) {
#pragma unroll
      for (int p = 0; p < 32; p++) {
        const float ar = sAs[IDX(p,r)];
        j0 += ar * sP[IDX(p,c0+0)];
        j1 += ar * sP[IDX(p,c0+1)];
        j2 += ar * sP[IDX(p,c0+2)];
        j3 += ar * sP[IDX(p,c0+3)];
      }
    }
    if (hpv) {
      j0 += sQisp[IDX(r,c0+0)];
      j1 += sQisp[IDX(r,c0+1)];
      j2 += sQisp[IDX(r,c0+2)];
      j3 += sQisp[IDX(r,c0+3)];
    }
    float4 v; v.x=j0; v.y=j1; v.z=j2; v.w=j3;
    *(float4*)(Jdb + ((size_t)(n*256 + t))*1024 + r*32 + c0) = v;
    if (tid < 32) {
      float h = Rm[t*32 + tid];
      if (hcv) {
        float a = 0.f;
#pragma unroll
        for (int j = 0; j < 32; j++) a += sP[IDX(tid,j)] * s_bs[j];
        h -= a;
      }
      if (hpv) {
        float a = 0.f;
#pragma unroll
        for (int j = 0; j < 32; j++) a += sQisp[IDX(tid,j)] * s_bsp[j];
        h += a;
      }
      h_ws[((size_t)(n*256 + t))*32 + tid] = h;
    }
  }
}

// ---------------- Phase 3: chunked chains ----------------
union __align__(16) ChainShared {
  struct {
    float sCT[32*36];
    float sB[32*36];
    float sPiv[64];
    float s_rhs[32], s_d[32], s_invp[32];
  } r0;
  struct {
    float sLl[32*36];
    float sLT[32*36];
    float sLrow[32*36];          // L stored by ROWS (filled during chol) for the column-sweep solve
    float sCol[32];
    float s_x[32], s_invd[32], s_invr[32];
  } r1;
};

__global__ __launch_bounds__(64) void chain_kernel(
    const float* __restrict__ Jdb, const float* __restrict__ Pm,
    const float* __restrict__ h_ws, const float* __restrict__ noise,
    float* __restrict__ c_ws, float* __restrict__ d_ws, float* __restrict__ x_ws) {
  const int bid  = blockIdx.x;
  const int role = (bid >= 64*NCH0) ? 1 : 0;
  const int rem  = bid - role*64*NCH0;
  const int bn   = rem & 63;
  const int ch   = rem >> 6;
  const int lane = threadIdx.x;
  const int r    = lane >> 1;
  const int h2   = lane & 1;
  const int c16  = h2 * 16;

  const int csz       = role ? CSZ1 : CSZ0;
  const int k_out     = ch * csz;
  const int k_start   = (ch == 0) ? 0 : (k_out - WARM);
  const int k_end_raw = k_out + csz;
  const int k_end     = (k_end_raw > 256) ? 256 : k_end_raw;

  const float* Jb = Jdb + (size_t)bn * 256 * 1024;
  const float* Pb = Pm  + (size_t)bn * 255 * 1024;

  __shared__ ChainShared su;

  if (role == 0) {
    // ============ GJ chain: J_k = Jdb_k + P_{k-1} c_{k-1}; staged-pivot Gauss-Jordan ============
    float* sCT = su.r0.sCT;
    float* sB  = su.r0.sB;
    float* sPiv = su.r0.sPiv;
    float* s_rhs = su.r0.s_rhs;
    float* s_d   = su.r0.s_d;
    float* s_invp = su.r0.s_invp;
    const float* hb = h_ws + (size_t)bn * 256 * 32;

    const int offO = c16;
    const int offX = 16 - c16;

    float jrow[16]; float4 pq[4]; float hq;
    {
      float4 j4[4];
#pragma unroll
      for (int q = 0; q < 4; q++) j4[q] = *(const float4*)(Jb + (size_t)k_start*1024 + r*32 + c16 + 4*q);
#pragma unroll
      for (int q = 0; q < 4; q++) pq[q] = *(const float4*)(Pb + (size_t)k_start*1024 + r*32 + c16 + 4*q);
      hq = hb[k_start*32 + r];
#pragma unroll
      for (int i = 0; i < 16; i++) jrow[i] = F4C(j4[i >> 2], i & 3);
    }

    for (int k = k_start; k < k_end; k++) {
      float4 jn4[4], pn[4]; float hn = 0.f;
      if (k + 1 < 256) {
#pragma unroll
        for (int q = 0; q < 4; q++)
          jn4[q] = *(const float4*)(Jb + (size_t)(k+1)*1024 + r*32 + c16 + 4*q);
        hn = hb[(k+1)*32 + r];
        if (k + 1 < 255) {
#pragma unroll
          for (int q = 0; q < 4; q++)
            pn[q] = *(const float4*)(Pb + (size_t)(k+1)*1024 + r*32 + c16 + 4*q);
        }
      }
      if (h2 == 0) s_rhs[r] = hq;
      float g[32];
      if (h2 == 1) {
#pragma unroll
        for (int i = 0; i < 32; i++) g[i] = (i == r) ? 1.f : 0.f;
      }
#pragma unroll
      for (int i = 0; i < 16; i++) {
        const float oth = __shfl_xor(jrow[i], 1);
        if (h2 == 0) { g[i] = jrow[i]; g[16+i] = oth; }
      }
      if (r == 0) {
#pragma unroll
        for (int q = 0; q < 8; q++) {
          float4 v; v.x=g[4*q]; v.y=g[4*q+1]; v.z=g[4*q+2]; v.w=g[4*q+3];
          *(float4*)(&sPiv[h2*32 + 4*q]) = v;
        }
      }
      WAVE_FENCE();
      float my_piv = 1.f;
#pragma unroll
      for (int j = 0; j < 32; j++) {
        const float pj_own = sPiv[h2*32 + j];
        const float pj_oth = __shfl_xor(pj_own, 1);
        const float dpiv = h2 ? pj_oth : pj_own;
        const float ip = __builtin_amdgcn_rcpf(dpiv);
        const float gj_own = g[j];
        const float gj_oth = __shfl_xor(gj_own, 1);
        float f = (h2 ? gj_oth : gj_own) * ip;
        if (j == r) { my_piv = dpiv; f = 0.f; }
#pragma unroll
        for (int q = 0; q < 8; q++) {
          const float4 v = *(const float4*)(&sPiv[h2*32 + 4*q]);
          g[4*q+0] -= f * v.x;
          g[4*q+1] -= f * v.y;
          g[4*q+2] -= f * v.z;
          g[4*q+3] -= f * v.w;
        }
        if (j + 1 < 32) {
          WAVE_FENCE();
          if (r == j + 1) {
#pragma unroll
            for (int q = 0; q < 8; q++) {
              float4 v; v.x=g[4*q]; v.y=g[4*q+1]; v.z=g[4*q+2]; v.w=g[4*q+3];
              *(float4*)(&sPiv[h2*32 + 4*q]) = v;
            }
          }
          WAVE_FENCE();
        }
      }
      const float ipv = __builtin_amdgcn_rcpf(my_piv);
      if (h2 == 0) s_invp[r] = ipv;
      else {
        const int s7 = r & 7;
#pragma unroll
        for (int q = 0; q < 8; q++) {
          float4 v; v.x=g[4*q]; v.y=g[4*q+1]; v.z=g[4*q+2]; v.w=g[4*q+3];
          *(float4*)(&sB[r*36 + 4*(q ^ s7)]) = v;
        }
      }
      WAVE_FENCE();
      if (h2 == 1) {
        float acc = 0.f;
#pragma unroll
        for (int q = 0; q < 8; q++) {
          const float4 rv = *(const float4*)(&s_rhs[4*q]);
          acc += g[4*q]*rv.x + g[4*q+1]*rv.y + g[4*q+2]*rv.z + g[4*q+3]*rv.w;
        }
        const float dv = acc * ipv;
        s_d[r] = dv;
        if (k >= k_out) d_ws[((size_t)(bn*256 + k))*32 + r] = dv;
      }
      float4 poK[4];
      if (k < 255) {
#pragma unroll
        for (int q = 0; q < 4; q++) poK[q] = xor1(pq[q]);
        float outv[16];
#pragma unroll
        for (int i = 0; i < 16; i++) {
          const int c = c16 + i;
          const float* bb = &sB[c*36];
          const int s7 = c & 7;
          float acc = 0.f;
#pragma unroll
          for (int q = 0; q < 4; q++) {
            const float4 v0 = *(const float4*)(bb + 4*((4*h2 + q) ^ s7));
            acc += pq[q].x*v0.x + pq[q].y*v0.y + pq[q].z*v0.z + pq[q].w*v0.w;
            const float4 v1 = *(const float4*)(bb + 4*(((4 - 4*h2) + q) ^ s7));
            acc += poK[q].x*v1.x + poK[q].y*v1.y + poK[q].z*v1.z + poK[q].w*v1.w;
          }
          outv[i] = -acc * s_invp[c];
        }
        if (k >= k_out) {
#pragma unroll
          for (int q = 0; q < 4; q++) {
            float4 v; v.x=outv[4*q]; v.y=outv[4*q+1]; v.z=outv[4*q+2]; v.w=outv[4*q+3];
            *(float4*)(c_ws + ((size_t)(bn*255 + k))*1024 + r*32 + c16 + 4*q) = v;
          }
        }
#pragma unroll
        for (int i = 0; i < 16; i++) sCT[(c16+i)*36 + r] = outv[i];
      }
      WAVE_FENCE();
      if (k + 1 < k_end) {
        float a_own = 0.f;
#pragma unroll
        for (int q = 0; q < 4; q++) {
          const float4 dv = *(const float4*)(&s_d[c16 + 4*q]);
          a_own += pq[q].x*dv.x + pq[q].y*dv.y + pq[q].z*dv.z + pq[q].w*dv.w;
        }
        hq = hn + a_own + __shfl_xor(a_own, 1);
#pragma unroll
        for (int i = 0; i < 16; i++) {
          const float* base = &sCT[(c16 + i) * 36];
          float acc = F4C(jn4[i >> 2], i & 3);
#pragma unroll
          for (int q = 0; q < 4; q++) {
            const float4 v0 = *(const float4*)(base + offO + 4*q);
            acc += pq[q].x*v0.x + pq[q].y*v0.y + pq[q].z*v0.z + pq[q].w*v0.w;
            const float4 v1 = *(const float4*)(base + offX + 4*q);
            acc += poK[q].x*v1.x + poK[q].y*v1.y + poK[q].z*v1.z + poK[q].w*v1.w;
          }
          jrow[i] = acc;
        }
#pragma unroll
        for (int q = 0; q < 4; q++) pq[q] = pn[q];
      }
    }
  } else {
    // ============ chol chain: M_k = Jdb_k - Ll Ll^T; staged-column Cholesky; Ll; x ============
    float* sLl   = su.r1.sLl;
    float* sLT   = su.r1.sLT;
    float* sLrow = su.r1.sLrow;
    float* sCol  = su.r1.sCol;
    float* s_x   = su.r1.s_x;
    float* s_invd = su.r1.s_invd;
    float* s_invr = su.r1.s_invr;
    const float* nb = noise + (size_t)bn * 8192;

    float mrow[16]; float4 pq[4]; float xr;
    {
      float4 j4[4];
#pragma unroll
      for (int q = 0; q < 4; q++) j4[q] = *(const float4*)(Jb + (size_t)k_start*1024 + r*32 + c16 + 4*q);
#pragma unroll
      for (int q = 0; q < 4; q++) pq[q] = *(const float4*)(Pb + (size_t)k_start*1024 + r*32 + c16 + 4*q);
      xr = nb[k_start*32 + r];
#pragma unroll
      for (int i = 0; i < 16; i++) mrow[i] = F4C(j4[i >> 2], i & 3);
    }

    for (int k = k_start; k < k_end; k++) {
      float4 jn4[4], pn[4]; float nn = 0.f;
      if (k + 1 < 256) {
#pragma unroll
        for (int q = 0; q < 4; q++)
          jn4[q] = *(const float4*)(Jb + (size_t)(k+1)*1024 + r*32 + c16 + 4*q);
        nn = nb[(k+1)*32 + r];
        if (k + 1 < 255) {
#pragma unroll
          for (int q = 0; q < 4; q++)
            pn[q] = *(const float4*)(Pb + (size_t)(k+1)*1024 + r*32 + c16 + 4*q);
        }
      }
      // cholesky on mrow with LDS-staged pivot column; fills sLT (cols) AND sLrow (rows)
#pragma unroll
      for (int j = 0; j < 32; j++) {
        const int jl = j & 15, jh = j >> 4;
        WAVE_FENCE();
        if (h2 == jh) sCol[r] = mrow[jl];
        WAVE_FENCE();
        const float dpiv = sCol[j];
        const float fr   = sCol[r];
        const float sq = sqrtf(dpiv);
        const float inv = __builtin_amdgcn_rcpf(sq);
        if (h2 == 0 && r >= j) {
          const float lv = (r == j) ? sq : fr*inv;
          sLT[36*j + 4*((r>>2) ^ (j&7)) + (r&3)] = lv;          // column j (for backsub)
          sLrow[36*r + 4*((j>>2) ^ (r&7)) + (j&3)] = lv;        // row r (for the sweep)
        }
        if (lane == 0) { s_invd[j] = inv; s_invr[j] = __builtin_amdgcn_rcpf(sq + EPS_BS); }
        const float s2 = (r > j) ? fr*inv*inv : 0.f;
#pragma unroll
        for (int q = 0; q < 4; q++) {
          const float4 cc = *(const float4*)(&sCol[c16 + 4*q]);
          mrow[4*q+0] -= s2 * cc.x;
          mrow[4*q+1] -= s2 * cc.y;
          mrow[4*q+2] -= s2 * cc.z;
          mrow[4*q+3] -= s2 * cc.w;
        }
      }
      WAVE_FENCE();
      // Ll row r via column-sweep back-substitution of L^T X = -P^T (X = Ll^T):
      // lane (r,h2) owns X rows [c16,c16+16) of column r, i.e. Ll[r][c16..c16+15].
      // sv[il] carries partial sum; finalized in place at pivot j = c16+il.
      float sv[16];
      if (k < 255) {
#pragma unroll
        for (int q = 0; q < 4; q++) {
          sv[4*q+0] = -pq[q].x; sv[4*q+1] = -pq[q].y;
          sv[4*q+2] = -pq[q].z; sv[4*q+3] = -pq[q].w;
        }
#pragma unroll
        for (int j = 31; j >= 0; j--) {
          const int jl = j & 15, jh = j >> 4;
          const float invdj = s_invd[j];
          const float v = sv[jl] * invdj;      // valid on owner half (h2==jh)
          const float w = __shfl_xor(v, 1);
          const float xj = (h2 == jh) ? v : w;
          if (h2 == jh) sv[jl] = v;            // finalized Ll[r][j]
          // s[i] -= L[j][i]*xj for i<j (own half); L row j broadcast from sLrow
#pragma unroll
          for (int q = 0; q < 4; q++) {
            if (4*q < j) {
              const float4 lv = *(const float4*)(&sLrow[36*j + 4*(((h2<<2)+q) ^ (j&7))]);
#pragma unroll
              for (int e = 0; e < 4; e++) {
                const int iLo = 4*q+e, iHi = 16+4*q+e;
                const float le = F4C(lv, e);
                if (iHi < j) {
                  sv[4*q+e] -= le * xj;                       // both halves active
                } else if (iLo < j) {
                  const float m = (h2 == 0) ? le : 0.f;        // NaN-safe mask
                  sv[4*q+e] -= m * xj;
                }
              }
            }
          }
        }
        // write Ll row r to sLl (both halves write their own chunks)
        const int s7r = r & 7;
#pragma unroll
        for (int q = 0; q < 4; q++) {
          float4 v4; v4.x=sv[4*q]; v4.y=sv[4*q+1]; v4.z=sv[4*q+2]; v4.w=sv[4*q+3];
          *(float4*)(&sLl[36*r + 4*(((h2<<2)+q) ^ s7r)]) = v4;
        }
      }
      WAVE_FENCE();
      // mrow-fold: mrow = Jdb_{k+1} - Ll_k Ll_k^T  (lrow from sv + DPP partner exchange)
      if (k + 1 < k_end) {
        float lrow[32];
#pragma unroll
        for (int gi = 0; gi < 16; gi++) {
          const float o = __shfl_xor(sv[gi], 1);
          lrow[gi]      = h2 ? o : sv[gi];
          lrow[16 + gi] = h2 ? sv[gi] : o;
        }
#pragma unroll
        for (int i = 0; i < 16; i++) {
          const int c = c16 + i;
          const int s7c = c & 7;
          float acc = 0.f;
#pragma unroll
          for (int q = 0; q < 8; q++) {
            const float4 v4 = *(const float4*)(&sLl[36*c + 4*(q ^ s7c)]);
            acc += lrow[4*q]*v4.x + lrow[4*q+1]*v4.y + lrow[4*q+2]*v4.z + lrow[4*q+3]*v4.w;
          }
          mrow[i] = F4C(jn4[i >> 2], i & 3) - acc;
        }
      }
      // x back-substitution: (L+eps)^T x = xr
      {
        float lc[32];
        const int s7r = r & 7;
#pragma unroll
        for (int q = 0; q < 8; q++) {
          const float4 v = *(const float4*)(&sLT[36*r + 4*(q ^ s7r)]);
          lc[4*q]=v.x; lc[4*q+1]=v.y; lc[4*q+2]=v.z; lc[4*q+3]=v.w;
        }
        float xp = xr;
        float myx = 0.f;
#pragma unroll
        for (int j = 31; j >= 0; j--) {
          const float xj = __shfl(xp * s_invr[j], 2*j);
          if (j == r) myx = xj;
          if (r < j) xp -= lc[j] * xj;
        }
        if (h2 == 0) {
          s_x[r] = myx;
          if (k >= k_out) x_ws[((size_t)(bn*256 + k))*32 + r] = myx;
        }
      }
      WAVE_FENCE();
      // xr-fold: xr = z_{k+1} - Ll_k^T x_k
      if (k + 1 < k_end) {
        float a_own = 0.f;
        const int rg = r >> 2, re = r & 3;
#pragma unroll
        for (int jj = 0; jj < 16; jj++)
          a_own += sLl[36*(c16+jj) + 4*(rg ^ (jj & 7)) + re] * s_x[c16+jj];
        xr = nn - (a_own + __shfl_xor(a_own, 1));
#pragma unroll
        for (int q = 0; q < 4; q++) pq[q] = pn[q];
      }
    }
  }
}

// ---------------- Phase 4: chunked backward mu scan + output = x + mu (single-wave) ----------
__global__ __launch_bounds__(64) void bwd_kernel(const float* __restrict__ c_ws,
                                                 const float* __restrict__ d_ws,
                                                 const float* __restrict__ x_ws,
                                                 float* __restrict__ out) {
  const int bn = blockIdx.x >> 4;
  const int q  = blockIdx.x & 15;
  const int lane = threadIdx.x;
  const int r = lane >> 1, h2 = lane & 1, c16 = h2 * 16;
  const int k_lo = q * 16;
  const int k_seed = (q == 15) ? 255 : (k_lo + 23);
  __shared__ float s_mu[32];
  if (h2 == 0) {
    const float mu = d_ws[((size_t)(bn*256 + k_seed))*32 + r];
    s_mu[r] = mu;
    if (k_seed == 255)
      out[((size_t)(bn*256 + 255))*32 + r] = x_ws[((size_t)(bn*256 + 255))*32 + r] + mu;
  }
  WAVE_FENCE();
  for (int k = k_seed - 1; k >= k_lo; k--) {
    const float* cp = c_ws + ((size_t)(bn*255 + k))*1024 + r*32 + c16;
    const float4 v0 = *(const float4*)(cp + 0);
    const float4 v1 = *(const float4*)(cp + 4);
    const float4 v2 = *(const float4*)(cp + 8);
    const float4 v3 = *(const float4*)(cp + 12);
    float part = v0.x*s_mu[c16+0] + v0.y*s_mu[c16+1] + v0.z*s_mu[c16+2] + v0.w*s_mu[c16+3]
               + v1.x*s_mu[c16+4] + v1.y*s_mu[c16+5] + v1.z*s_mu[c16+6] + v1.w*s_mu[c16+7]
               + v2.x*s_mu[c16+8] + v2.y*s_mu[c16+9] + v2.z*s_mu[c16+10]+ v2.w*s_mu[c16+11]
               + v3.x*s_mu[c16+12]+ v3.y*s_mu[c16+13]+ v3.z*s_mu[c16+14]+ v3.w*s_mu[c16+15];
    part += __shfl_xor(part, 1);
    float mu = 0.f, xv = 0.f;
    if (h2 == 0) {
      mu = d_ws[((size_t)(bn*256 + k))*32 + r] - part;
      xv = x_ws[((size_t)(bn*256 + k))*32 + r];
    }
    WAVE_FENCE();
    if (h2 == 0) {
      s_mu[r] = mu;
      if (k < k_lo + 16) out[((size_t)(bn*256 + k))*32 + r] = xv + mu;
    }
    WAVE_FENCE();
  }
}

extern "C" void kernel_launch(void* const* d_in, const int* in_sizes, int n_in,
                              void* d_out, int out_size, void* d_ws, size_t ws_size,
                              hipStream_t stream) {
  const float* z      = (const float*)d_in[0];   // (64,256,8)
  const float* A_base = (const float*)d_in[1];   // (8,32,32)
  const float* b_base = (const float*)d_in[2];   // (8,32)
  const float* Q_sqrt = (const float*)d_in[3];   // (8,32,32)
  const float* ms     = (const float*)d_in[4];   // (256,32)
  const float* Ri     = (const float*)d_in[5];   // (256,32,32)
  const float* noise  = (const float*)d_in[6];   // (64,8192)
  float* out = (float*)d_out;

  float* ws = (float*)d_ws;
  const size_t SZ_C = (size_t)64*255*1024;
  const size_t SZ_J = (size_t)64*256*1024;
  const size_t SZ_V = (size_t)64*256*32;

  float* c_ws  = ws;
  float* Jdb   = c_ws + SZ_C;
  float* Pm    = Jdb + SZ_J;
  float* hbuf  = Pm + SZ_C;
  float* d_vec = hbuf + SZ_V;
  float* x_vec = d_vec + SZ_V;
  float* Ris   = x_vec + SZ_V;
  float* Rm    = Ris + (size_t)256*1024;

  ris_kernel<<<256, 256, 0, stream>>>(Ri, ms, Ris, Rm);
  pre_kernel<<<16384, 256, 0, stream>>>(z, A_base, b_base, Q_sqrt, Ris, Rm, Jdb, Pm, hbuf);
  chain_kernel<<<64*(NCH0+NCH1), 64, 0, stream>>>(Jdb, Pm, hbuf, noise, c_ws, d_vec, x_vec);
  bwd_kernel<<<1024, 64, 0, stream>>>(c_ws, d_vec, x_vec, out);
}